// Round 2
// baseline (1579.422 us; speedup 1.0000x reference)
//
#include <hip/hip_runtime.h>
#include <hip/hip_bf16.h>

typedef __bf16 bf16x8 __attribute__((ext_vector_type(8)));
typedef float f32x4 __attribute__((ext_vector_type(4)));

#define S_LEN 4096
#define EMB   512
#define NHEAD 8
#define HDIM  64
#define NBAT  2
#define NROW  (NBAT * S_LEN)   // 8192

static __device__ __forceinline__ f32x4 mfma16x16(bf16x8 a, bf16x8 b, f32x4 c) {
    return __builtin_amdgcn_mfma_f32_16x16x32_bf16(a, b, c, 0, 0, 0);
}

// ---------------- convert fp32 -> bf16 ----------------
__global__ __launch_bounds__(256) void convert_kernel(
    const float* __restrict__ x, const float* __restrict__ Wq,
    const float* __restrict__ Wk, const float* __restrict__ Wv,
    const float* __restrict__ Wo,
    __hip_bfloat16* __restrict__ xb, __hip_bfloat16* __restrict__ wqkv,
    __hip_bfloat16* __restrict__ wob)
{
    const int NX = NROW * EMB;     // 4194304
    const int NW = EMB * EMB;      // 262144 = 2^18
    int i = blockIdx.x * 256 + threadIdx.x;
    if (i < NX) { xb[i] = __float2bfloat16(x[i]); return; }
    int j = i - NX;
    if (j < 3 * NW) {
        int p = j >> 18, r = j & (NW - 1);
        const float* src = (p == 0) ? Wq : (p == 1) ? Wk : Wv;
        wqkv[j] = __float2bfloat16(src[r]);
    } else if (j < 4 * NW) {
        int r = j - 3 * NW;
        wob[r] = __float2bfloat16(Wo[r]);
    }
}

// ---------------- shared GEMM mainloop ----------------
__device__ __forceinline__ void gemm_core(
    const __hip_bfloat16* __restrict__ A, const __hip_bfloat16* __restrict__ Bw,
    int mbase, int nbase,
    __hip_bfloat16* As, __hip_bfloat16* Bs, f32x4 acc[2][4])
{
    const int tid = threadIdx.x;
    const int w = tid >> 6, lane = tid & 63, l = lane & 15, quad = lane >> 4;
    const f32x4 zero = {0.f, 0.f, 0.f, 0.f};
#pragma unroll
    for (int mb = 0; mb < 2; mb++)
#pragma unroll
        for (int nb = 0; nb < 4; nb++) acc[mb][nb] = zero;

    for (int k0 = 0; k0 < EMB; k0 += 32) {
        __syncthreads();
#pragma unroll
        for (int c = tid; c < 512; c += 256) {
            int row = c >> 2, kc = c & 3;
            uint4 v = *(const uint4*)(A + (size_t)(mbase + row) * EMB + k0 + kc * 8);
            *(uint4*)(As + row * 40 + kc * 8) = v;
        }
        {
            int row = tid >> 2, kc = tid & 3;
            uint4 v = *(const uint4*)(Bw + (size_t)(nbase + row) * EMB + k0 + kc * 8);
            *(uint4*)(Bs + row * 40 + kc * 8) = v;
        }
        __syncthreads();

        bf16x8 af[2], bfr[4];
#pragma unroll
        for (int mb = 0; mb < 2; mb++)
            af[mb] = *(const bf16x8*)(As + (w * 32 + mb * 16 + l) * 40 + quad * 8);
#pragma unroll
        for (int nb = 0; nb < 4; nb++)
            bfr[nb] = *(const bf16x8*)(Bs + (nb * 16 + l) * 40 + quad * 8);
#pragma unroll
        for (int mb = 0; mb < 2; mb++)
#pragma unroll
            for (int nb = 0; nb < 4; nb++)
                acc[mb][nb] = mfma16x16(af[mb], bfr[nb], acc[mb][nb]);
    }
}

// ---------------- QKV projection ----------------
// All of Q,K,V written coalesced as [h][b][s][d]; V transposed later by vtrans.
__global__ __launch_bounds__(256, 4) void qkv_gemm(
    const __hip_bfloat16* __restrict__ xb, const __hip_bfloat16* __restrict__ wqkv,
    const float* __restrict__ bq, const float* __restrict__ bk, const float* __restrict__ bv,
    __hip_bfloat16* __restrict__ Qh, __hip_bfloat16* __restrict__ Kh,
    __hip_bfloat16* __restrict__ Vh)
{
    __shared__ __align__(16) __hip_bfloat16 As[128 * 40];
    __shared__ __align__(16) __hip_bfloat16 Bs[64 * 40];
    const int mbase = blockIdx.x * 128, nbase = blockIdx.y * 64;
    f32x4 acc[2][4];
    gemm_core(xb, wqkv, mbase, nbase, As, Bs, acc);

    const int tid = threadIdx.x;
    const int w = tid >> 6, lane = tid & 63, l = lane & 15, quad = lane >> 4;
    const int p = nbase >> 9;  // 0=Q,1=K,2=V (uniform per block)
    const float* bias = (p == 0) ? bq : (p == 1) ? bk : bv;
    __hip_bfloat16* dst = (p == 0) ? Qh : (p == 1) ? Kh : Vh;
#pragma unroll
    for (int mb = 0; mb < 2; mb++)
#pragma unroll
        for (int nb = 0; nb < 4; nb++)
#pragma unroll
            for (int r = 0; r < 4; r++) {
                int m = mbase + w * 32 + mb * 16 + quad * 4 + r;
                int n = nbase + nb * 16 + l;
                int o = n & 511;
                float v = acc[mb][nb][r] + bias[o];
                int b = m >> 12, s = m & 4095, hh = o >> 6, d = o & 63;
                dst[((size_t)((hh * 2 + b) * 4096 + s)) * 64 + d] = __float2bfloat16(v);
            }
}

// ---------------- V transpose: [hb][s][d] -> [hb][d][s] ----------------
__global__ __launch_bounds__(256) void vtrans(
    const __hip_bfloat16* __restrict__ Vh, __hip_bfloat16* __restrict__ Vt)
{
    __shared__ __align__(16) __hip_bfloat16 T[64 * 72];
    const int st = blockIdx.x, hb = blockIdx.y, tid = threadIdx.x;
    const int s0 = st * 64;
    const __hip_bfloat16* src = Vh + ((size_t)hb * 4096 + s0) * 64;
#pragma unroll
    for (int i = 0; i < 2; i++) {
        int c = tid + 256 * i, row = c >> 3, ch = c & 7;
        uint4 v = *(const uint4*)(src + row * 64 + ch * 8);
        *(uint4*)(T + row * 72 + ch * 8) = v;
    }
    __syncthreads();
#pragma unroll
    for (int i = 0; i < 2; i++) {
        int c = tid + 256 * i, d = c >> 3, ch = c & 7;
        __hip_bfloat16 tmp[8];
#pragma unroll
        for (int j = 0; j < 8; j++) tmp[j] = T[(ch * 8 + j) * 72 + d];
        *(uint4*)(Vt + ((size_t)(hb * 64 + d)) * 4096 + s0 + ch * 8) = *(uint4*)tmp;
    }
}

// ---------------- flash attention ----------------
// Block: (qt in 0..127, h). 32 q-rows, BOTH batches. 4 waves: wave w ->
// batch w&1, q-subtile w>>1. Register prefetch of KV + bias/mask one k-tile
// ahead: issued right after barrier B so the NEXT barrier A's vmcnt(0) drain
// finds them complete (latency hidden behind the compute phase).
__global__ __launch_bounds__(256, 3) void attn_kernel(
    const __hip_bfloat16* __restrict__ Qh, const __hip_bfloat16* __restrict__ Kh,
    const __hip_bfloat16* __restrict__ Vt,
    const float* __restrict__ bias, const int* __restrict__ mask,
    __hip_bfloat16* __restrict__ Om)
{
    const int h = blockIdx.y, qt = blockIdx.x;
    const int tid = threadIdx.x;
    const int w = tid >> 6, lane = tid & 63, l = lane & 15, quad = lane >> 4;
    const int bw = w & 1, wq = w >> 1;
    const int qr = qt * 32 + wq * 16;    // this wave's first q-row
    const float CS = 0.18033688011112042f;  // (1/8) * log2(e)

    __shared__ __align__(16) __hip_bfloat16 Ks[2][64 * 72];
    __shared__ __align__(16) __hip_bfloat16 Vs[2][64 * 72];
    __shared__ __align__(16) __hip_bfloat16 Ps[4][16 * 72];
    __hip_bfloat16* ps = Ps[w];

    // Q fragments (A-layout): row = qr + l, k = ks*32 + quad*8 + j
    const __hip_bfloat16* qp = Qh + ((size_t)((h * 2 + bw) * 4096 + qr + l)) * 64;
    bf16x8 qf0 = *(const bf16x8*)(qp + quad * 8);
    bf16x8 qf1 = *(const bf16x8*)(qp + 32 + quad * 8);

    const float* bptr = bias + (size_t)h * S_LEN * S_LEN;

    f32x4 oacc[4];
    float mst[4], lst[4];
    const f32x4 zero = {0.f, 0.f, 0.f, 0.f};
#pragma unroll
    for (int nb = 0; nb < 4; nb++) oacc[nb] = zero;
#pragma unroll
    for (int r = 0; r < 4; r++) { mst[r] = -__builtin_inff(); lst[r] = 0.f; }

    uint4 kvbuf[8];
    float bbuf[4][4];
    int   mbuf[4][4];

    auto kv_load = [&](int k0) {
#pragma unroll
        for (int i = 0; i < 8; i++) {
            int c = tid + 256 * i;
            int b = (c >> 9) & 1, isV = c >> 10;
            int row = (c >> 3) & 63, ch = c & 7;
            const __hip_bfloat16* src = isV
                ? Vt + ((size_t)((h * 2 + b) * 64 + row)) * 4096 + k0 + ch * 8
                : Kh + ((size_t)((h * 2 + b) * 4096 + k0 + row)) * 64 + ch * 8;
            kvbuf[i] = *(const uint4*)src;
        }
    };
    auto bm_load = [&](int k0) {
#pragma unroll
        for (int nb = 0; nb < 4; nb++)
#pragma unroll
            for (int r = 0; r < 4; r++) {
                size_t off = (size_t)(qr + quad * 4 + r) * S_LEN + k0 + nb * 16 + l;
                bbuf[nb][r] = bptr[off];
                mbuf[nb][r] = mask[off];
            }
    };

    kv_load(0);
    bm_load(0);

    for (int kt = 0; kt < 64; kt++) {
        __syncthreads();   // A: prior readers done; drains prefetch loads
        // write prefetched KV tile to LDS
#pragma unroll
        for (int i = 0; i < 8; i++) {
            int c = tid + 256 * i;
            int b = (c >> 9) & 1, isV = c >> 10;
            int row = (c >> 3) & 63, ch = c & 7;
            *(uint4*)((isV ? Vs[b] : Ks[b]) + row * 72 + ch * 8) = kvbuf[i];
        }
        __syncthreads();   // B: LDS tile visible

        // fold current bias/mask fragment (values arrived before barrier A)
        float bor[4][4];
#pragma unroll
        for (int nb = 0; nb < 4; nb++)
#pragma unroll
            for (int r = 0; r < 4; r++)
                bor[nb][r] = mbuf[nb][r] ? bbuf[nb][r] : -1e30f;

        // issue next-tile prefetch (drained at next barrier A)
        int k0n = (kt < 63) ? (kt + 1) * 64 : kt * 64;
        kv_load(k0n);
        bm_load(k0n);

        // S = Q K^T for this wave's batch
        f32x4 sc[4] = {zero, zero, zero, zero};
#pragma unroll
        for (int nb = 0; nb < 4; nb++) {
            bf16x8 kf0 = *(const bf16x8*)(Ks[bw] + (nb * 16 + l) * 72 + quad * 8);
            bf16x8 kf1 = *(const bf16x8*)(Ks[bw] + (nb * 16 + l) * 72 + 32 + quad * 8);
            sc[nb] = mfma16x16(qf0, kf0, sc[nb]);
            sc[nb] = mfma16x16(qf1, kf1, sc[nb]);
        }

        // online softmax (exp2 domain)
        float xv[4][4], rmax[4];
#pragma unroll
        for (int r = 0; r < 4; r++) rmax[r] = -__builtin_inff();
#pragma unroll
        for (int nb = 0; nb < 4; nb++)
#pragma unroll
            for (int r = 0; r < 4; r++) {
                xv[nb][r] = (sc[nb][r] + bor[nb][r]) * CS;
                rmax[r] = fmaxf(rmax[r], xv[nb][r]);
            }
#pragma unroll
        for (int r = 0; r < 4; r++) {
            rmax[r] = fmaxf(rmax[r], __shfl_xor(rmax[r], 1));
            rmax[r] = fmaxf(rmax[r], __shfl_xor(rmax[r], 2));
            rmax[r] = fmaxf(rmax[r], __shfl_xor(rmax[r], 4));
            rmax[r] = fmaxf(rmax[r], __shfl_xor(rmax[r], 8));
        }
        float alpha[4], rsum[4];
#pragma unroll
        for (int r = 0; r < 4; r++) {
            float mn = fmaxf(mst[r], rmax[r]);
            alpha[r] = __builtin_amdgcn_exp2f(mst[r] - mn);
            mst[r] = mn;
            rsum[r] = 0.f;
        }
        float pv[4][4];
#pragma unroll
        for (int nb = 0; nb < 4; nb++)
#pragma unroll
            for (int r = 0; r < 4; r++) {
                float e = __builtin_amdgcn_exp2f(xv[nb][r] - mst[r]);
                pv[nb][r] = e;
                rsum[r] += e;
            }
#pragma unroll
        for (int r = 0; r < 4; r++) {
            rsum[r] += __shfl_xor(rsum[r], 1);
            rsum[r] += __shfl_xor(rsum[r], 2);
            rsum[r] += __shfl_xor(rsum[r], 4);
            rsum[r] += __shfl_xor(rsum[r], 8);
            lst[r] = lst[r] * alpha[r] + rsum[r];
        }
#pragma unroll
        for (int nb = 0; nb < 4; nb++)
#pragma unroll
            for (int r = 0; r < 4; r++) oacc[nb][r] *= alpha[r];

        // P -> LDS (wave-private region: no barrier needed)
#pragma unroll
        for (int nb = 0; nb < 4; nb++)
#pragma unroll
            for (int r = 0; r < 4; r++)
                ps[(quad * 4 + r) * 72 + nb * 16 + l] = __float2bfloat16(pv[nb][r]);

        // O += P V
#pragma unroll
        for (int ks = 0; ks < 2; ks++) {
            bf16x8 pf = *(const bf16x8*)(ps + l * 72 + ks * 32 + quad * 8);
#pragma unroll
            for (int nb = 0; nb < 4; nb++) {
                bf16x8 vf = *(const bf16x8*)(Vs[bw] + (nb * 16 + l) * 72 + ks * 32 + quad * 8);
                oacc[nb] = mfma16x16(pf, vf, oacc[nb]);
            }
        }
    }

    // epilogue: Om[b*4096+q][h*64+d] = O/l
#pragma unroll
    for (int nb = 0; nb < 4; nb++)
#pragma unroll
        for (int r = 0; r < 4; r++) {
            int qq = qr + quad * 4 + r;
            float val = oacc[nb][r] / lst[r];
            Om[((size_t)(bw * 4096 + qq)) * 512 + h * 64 + nb * 16 + l] =
                __float2bfloat16(val);
        }
}

// ---------------- output projection ----------------
__global__ __launch_bounds__(256, 4) void out_gemm(
    const __hip_bfloat16* __restrict__ Om, const __hip_bfloat16* __restrict__ wob,
    const float* __restrict__ bo, float* __restrict__ out)
{
    __shared__ __align__(16) __hip_bfloat16 As[128 * 40];
    __shared__ __align__(16) __hip_bfloat16 Bs[64 * 40];
    const int mbase = blockIdx.x * 128, nbase = blockIdx.y * 64;
    f32x4 acc[2][4];
    gemm_core(Om, wob, mbase, nbase, As, Bs, acc);

    const int tid = threadIdx.x;
    const int w = tid >> 6, lane = tid & 63, l = lane & 15, quad = lane >> 4;
#pragma unroll
    for (int mb = 0; mb < 2; mb++)
#pragma unroll
        for (int nb = 0; nb < 4; nb++)
#pragma unroll
            for (int r = 0; r < 4; r++) {
                int m = mbase + w * 32 + mb * 16 + quad * 4 + r;
                int n = nbase + nb * 16 + l;
                out[(size_t)m * EMB + n] = acc[mb][nb][r] + bo[n];
            }
}

extern "C" void kernel_launch(void* const* d_in, const int* in_sizes, int n_in,
                              void* d_out, int out_size, void* d_ws, size_t ws_size,
                              hipStream_t stream) {
    const float* x    = (const float*)d_in[0];
    const float* bias = (const float*)d_in[1];
    const int*   mask = (const int*)d_in[2];
    const float* Wq   = (const float*)d_in[3];
    const float* bq   = (const float*)d_in[4];
    const float* Wk   = (const float*)d_in[5];
    const float* bk   = (const float*)d_in[6];
    const float* Wv   = (const float*)d_in[7];
    const float* bv   = (const float*)d_in[8];
    const float* Wo   = (const float*)d_in[9];
    const float* bo   = (const float*)d_in[10];
    float* out = (float*)d_out;

    char* ws = (char*)d_ws;
    __hip_bfloat16* xb   = (__hip_bfloat16*)ws; ws += (size_t)NROW * EMB * 2;
    __hip_bfloat16* wqkv = (__hip_bfloat16*)ws; ws += (size_t)3 * EMB * EMB * 2;
    __hip_bfloat16* wob  = (__hip_bfloat16*)ws; ws += (size_t)EMB * EMB * 2;
    __hip_bfloat16* Qh   = (__hip_bfloat16*)ws; ws += (size_t)NROW * EMB * 2;
    __hip_bfloat16* Kh   = (__hip_bfloat16*)ws; ws += (size_t)NROW * EMB * 2;
    __hip_bfloat16* Vh   = (__hip_bfloat16*)ws; ws += (size_t)NROW * EMB * 2;
    __hip_bfloat16* Om   = (__hip_bfloat16*)ws; ws += (size_t)NROW * EMB * 2;
    __hip_bfloat16* Vt   = xb;  // alias: xb is dead after qkv_gemm, vtrans runs after

    // 1) fp32 -> bf16
    convert_kernel<<<dim3(20480), dim3(256), 0, stream>>>(
        x, Wq, Wk, Wv, Wo, xb, wqkv, wob);
    // 2) fused QKV projection: M=8192, N=1536, K=512 (all coalesced writes)
    qkv_gemm<<<dim3(64, 24), dim3(256), 0, stream>>>(
        xb, wqkv, bq, bk, bv, Qh, Kh, Vh);
    // 3) V transpose [hb][s][d] -> [hb][d][s]
    vtrans<<<dim3(64, 16), dim3(256), 0, stream>>>(Vh, Vt);
    // 4) flash attention, 1024 blocks, software-pipelined
    attn_kernel<<<dim3(128, NHEAD), dim3(256), 0, stream>>>(
        Qh, Kh, Vt, bias, mask, Om);
    // 5) output projection: M=8192, N=512, K=512
    out_gemm<<<dim3(64, 8), dim3(256), 0, stream>>>(Om, wob, bo, out);
}